// Round 17
// baseline (174.560 us; speedup 1.0000x reference)
//
#include <hip/hip_runtime.h>

#define HW   256
#define HW2  (HW * HW)
#define CIN  64
#define COUT 64

#define RXN   7              // deform window rows: padded row coords c0-2 .. c0+4
#define CYN   70             // deform window cols: padded col coords r0-2 .. r0+67
#define NSITE (RXN * CYN)    // 490
#define SSTR  48             // bytes/site: 16 bf16 planes (32B) + 16B pad; 16-aligned

#define ONS   198            // offs window sites: 66 rows x 3 cols
#define OSTR  144            // bytes/site: 64 bf16 planes + 16B pad; 16-aligned

#define SOFF_BYTES 4608      // 18 ch x 64 rows x f32 offset table

typedef __attribute__((ext_vector_type(8))) short    short8v;   // 8 bf16
typedef __attribute__((ext_vector_type(4))) float    f32x4;
typedef __attribute__((ext_vector_type(4))) unsigned uint4v;

__device__ __forceinline__ unsigned short f2bf(float f) {      // RNE fp32->bf16
  unsigned u = __float_as_uint(f);
  u = u + 0x7FFFu + ((u >> 16) & 1u);
  return (unsigned short)(u >> 16);
}
__device__ __forceinline__ unsigned cvt_pk_bf16(float lo, float hi) {
  unsigned r;                                        // {hi16: bf16(hi), lo16: bf16(lo)}
  asm("v_cvt_pk_bf16_f32 %0, %1, %2" : "=v"(r) : "v"(lo), "v"(hi));
  return r;
}

// ---------------------------------------------------------------------------
// Kernel W (verified R8/R12, unchanged): deform weights wf (bf16) +
// offs weights wf2 (bf16), tap-pair fragment order.
// ---------------------------------------------------------------------------
__global__ void wfrag_kernel(const float* __restrict__ w, const float* __restrict__ pw,
                             short* __restrict__ wf, short* __restrict__ wf2) {
  const int T = blockIdx.x * 256 + threadIdx.x;      // 5120 + 2560 fragments
  if (T < 5120) {
    const int l    = T & 63;
    const int t    = (T >> 6) & 3;
    const int g    = T >> 8;                         // rho*5 + j
    const int j    = g % 5;
    const int rho  = g / 5;
    const int half = (l >> 5) & 1;
    const int oct  = (l >> 4) & 1;
    const int n    = 2 * j + half;
    const int oc   = t * 16 + (l & 15);
    const int ic0  = rho * 16 + oct * 8;
    short8v v;
#pragma unroll
    for (int e = 0; e < 8; ++e)
      v[e] = (n < 9) ? (short)f2bf(w[(oc * CIN + ic0 + e) * 9 + n]) : (short)0;
    *(short8v*)(wf + (size_t)T * 8) = v;
  } else if (T < 7680) {
    const int T2   = T - 5120;
    const int l    = T2 & 63;
    const int t    = (T2 >> 6) & 1;
    const int g    = T2 >> 7;                        // rho*5 + j
    const int j    = g % 5;
    const int rho  = g / 5;
    const int half = (l >> 5) & 1;
    const int oct  = (l >> 4) & 1;
    const int n    = 2 * j + half;
    const int oc   = t * 16 + (l & 15);
    const int ic0  = rho * 16 + oct * 8;
    short8v v;
#pragma unroll
    for (int e = 0; e < 8; ++e)
      v[e] = (n < 9 && oc < 18) ? (short)f2bf(pw[(oc * CIN + ic0 + e) * 9 + n])
                                : (short)0;
    *(short8v*)(wf2 + (size_t)T2 * 8) = v;
  }
}

// ---------------------------------------------------------------------------
// FUSED kernel (R15 structure): phase A = offs conv via MFMA -> 18x64 offset
// table in LDS; phase B = verified R12 deform reading offsets from LDS.
// CHANGE vs R15: amdgpu_waves_per_eu(2,3) -- the fused kernel's live state
// (~135 regs) exceeded the 4-waves/EU allocation (104 regs, 23MB spill
// writes). 3 waves/EU lets the allocator keep the pipeline in registers;
// R11->R12 showed spill-elimination beats the occupancy loss.
// All arithmetic bit-identical to R12/R15 -> absmax must stay 0.03125.
// ---------------------------------------------------------------------------
__global__ __launch_bounds__(256)
__attribute__((amdgpu_waves_per_eu(2, 3)))
void fused_kernel(
    const float* __restrict__ x, const short* __restrict__ wf,
    const short* __restrict__ wf2, const float* __restrict__ pb,
    float* __restrict__ out)
{
  __shared__ __align__(16) char smem[SOFF_BYTES + ONS * OSTR];  // 33,120 B
  float* sOffT = (float*)smem;                      // [ch 0..17][rr 0..63]
  char*  sow   = smem + SOFF_BYTES;                 // offs window (phase A)
  char*  sxb   = smem + SOFF_BYTES;                 // deform window (phase B)

  const int b    = blockIdx.y;
  const int bx   = blockIdx.x;                      // 4 r-tiles * 256 cols
  const int r0   = (bx & 3) * 64;
  const int c0   = bx >> 2;
  const int tid  = threadIdx.x;
  const int lane = tid & 63;
  const int i    = lane & 15;
  const int a    = (lane >> 4) & 3;
  const int oct  = a & 1;
  const int half = a >> 1;
  const int wv   = tid >> 6;
  const int rr   = wv * 16 + i;                     // pixel row within tile
  const int r    = r0 + rr;                         // this thread's pixel row

  const float* xb = x + (size_t)b * CIN * HW2;

  // ======================= Phase A: offset conv ==========================
  // stage 64 planes of the 66x3 window (zeros outside image)
  if (tid < ONS) {
    const int rl = tid / 3, kw = tid - rl * 3;
    const int rw = r0 - 1 + rl;                     // image row
    const int cc = c0 - 1 + kw;                     // image col
    const bool ok = (rw >= 0) & (rw < HW) & (cc >= 0) & (cc < HW);
    const float* xq = xb + (size_t)max(rw, 0) * HW + max(cc, 0);
    char* dst = sow + tid * OSTR;
#pragma unroll
    for (int m8 = 0; m8 < 8; ++m8) {
      uint4v v;
#pragma unroll
      for (int mm = 0; mm < 4; ++mm) {
        const int pl = m8 * 8 + mm * 2;
        const float v0 = ok ? xq[(size_t)pl * HW2] : 0.f;
        const float v1 = ok ? xq[(size_t)(pl + 1) * HW2] : 0.f;
        v[mm] = cvt_pk_bf16(v0, v1);
      }
      *(uint4v*)(dst + m8 * 16) = v;
    }
  }
  __syncthreads();

  {
    f32x4 acc0 = (f32x4){0.f, 0.f, 0.f, 0.f};
    f32x4 acc1 = (f32x4){0.f, 0.f, 0.f, 0.f};
#pragma unroll
    for (int rho = 0; rho < 4; ++rho) {
#pragma unroll
      for (int j = 0; j < 5; ++j) {
        const int n  = 2 * j + half;
        const int nn = (n < 9) ? n : 0;             // tap 9: zero A-weights
        const int kh = nn / 3, kw = nn - kh * 3;
        const int site = (rr + kh) * 3 + kw;
        const short8v bfr = *(const short8v*)(sow + site * OSTR + rho * 32 + oct * 16);
        const short* wfb = wf2 + ((size_t)(((rho * 5 + j) * 2) * 64) + lane) * 8;
        const short8v a0 = *(const short8v*)(wfb);
        const short8v a1 = *(const short8v*)(wfb + 64 * 8);
        acc0 = __builtin_amdgcn_mfma_f32_16x16x32_bf16(a0, bfr, acc0, 0, 0, 0);
        acc1 = __builtin_amdgcn_mfma_f32_16x16x32_bf16(a1, bfr, acc1, 0, 0, 0);
      }
    }
    // write offsets to LDS table: ch = a*4+jj (t=0), 16+jj (t=1, a==0)
#pragma unroll
    for (int jj = 0; jj < 4; ++jj) {
      const int ch = a * 4 + jj;
      sOffT[ch * 64 + rr] = acc0[jj] + pb[ch];
    }
    if (a == 0) {
#pragma unroll
      for (int jj = 0; jj < 2; ++jj) {
        const int ch = 16 + jj;
        sOffT[ch * 64 + rr] = acc1[jj] + pb[ch];
      }
    }
  }
  __syncthreads();                                  // sOffT ready; sow dead

  // ======================= Phase B: deform (R12) ==========================
  unsigned qsite[5];
  float    qwx[5], qwy[5];
  unsigned inwm = 0;
#pragma unroll
  for (int t5 = 0; t5 < 5; ++t5) {
    const int  n9  = 2 * t5 + half;
    const bool pad = (n9 >= 9);
    const int  n   = pad ? 0 : n9;
    const float ox = sOffT[n * 64 + rr];
    const float oy = sOffT[(9 + n) * 64 + rr];
    const float px = (float)(c0 + (n % 3)) + ox;    // transposed base: row ~ c
    const float py = (float)(r + (n / 3)) + oy;     // col ~ r
    const float fx = floorf(px);
    const float fy = floorf(py);
    const int ltx = (int)fx, lty = (int)fy;
    const bool okc = (ltx >= 0) & (lty >= 0) & (ltx + 1 <= HW + 1) & (lty + 1 <= HW + 1);
    const int lx = ltx - c0 + 2;                    // window-local row
    const int ly = lty - r0 + 2;                    // window-local col
    const bool inw = okc & (lx >= 0) & (lx <= RXN - 2) & (ly >= 0) & (ly <= CYN - 2);
    qsite[t5] = (pad || !inw) ? 0u : (unsigned)(lx * CYN + ly);
    qwx[t5]   = 1.f + fx - px;                      // wxl (exact in fast path)
    qwy[t5]   = 1.f + fy - py;                      // wyl
    inwm |= ((inw || pad) ? 1u : 0u) << t5;
  }

  // staging site descriptors (sites tid and tid+256)
  const int s1 = tid, s2 = tid + 256;
  int gi1 = 0, gi2 = 0; bool ok1, ok2;
  {
    const int rxl = s1 / CYN, cyl = s1 - rxl * CYN;
    const int rx = c0 - 2 + rxl, cyp = r0 - 2 + cyl;
    ok1 = (rx >= 1) & (rx <= HW) & (cyp >= 1) & (cyp <= HW);
    if (ok1) gi1 = (rx - 1) * HW + (cyp - 1);
  }
  {
    const int rxl = s2 / CYN, cyl = s2 - rxl * CYN;
    const int rx = c0 - 2 + rxl, cyp = r0 - 2 + cyl;
    ok2 = (s2 < NSITE) & (rx >= 1) & (rx <= HW) & (cyp >= 1) & (cyp <= HW);
    if (ok2) gi2 = (rx - 1) * HW + (cyp - 1);
  }

  // T14 pipeline registers: round's 32 staging floats
  float pv1[16], pv2[16];

#define LOADR(RHO)                                                         \
  {                                                                        \
    const float* xsrc = xb + (size_t)((RHO) * 16) * HW2;                   \
    _Pragma("unroll")                                                      \
    for (int m = 0; m < 16; ++m) {                                         \
      const float* xp = xsrc + (size_t)m * HW2;                            \
      pv1[m] = ok1 ? xp[gi1] : 0.f;                                        \
      pv2[m] = ok2 ? xp[gi2] : 0.f;                                        \
    }                                                                      \
  }

#define WRITES()                                                           \
  {                                                                        \
    uint4v w0, w1;                                                         \
    _Pragma("unroll")                                                      \
    for (int m = 0; m < 4; ++m) w0[m] = cvt_pk_bf16(pv1[2*m], pv1[2*m+1]); \
    _Pragma("unroll")                                                      \
    for (int m = 0; m < 4; ++m) w1[m] = cvt_pk_bf16(pv1[8+2*m], pv1[9+2*m]);\
    *(uint4v*)(sxb + s1 * SSTR)      = w0;                                 \
    *(uint4v*)(sxb + s1 * SSTR + 16) = w1;                                 \
    if (s2 < NSITE) {                                                      \
      uint4v u0, u1;                                                       \
      _Pragma("unroll")                                                    \
      for (int m = 0; m < 4; ++m) u0[m] = cvt_pk_bf16(pv2[2*m], pv2[2*m+1]);\
      _Pragma("unroll")                                                    \
      for (int m = 0; m < 4; ++m) u1[m] = cvt_pk_bf16(pv2[8+2*m], pv2[9+2*m]);\
      *(uint4v*)(sxb + s2 * SSTR)      = u0;                               \
      *(uint4v*)(sxb + s2 * SSTR + 16) = u1;                               \
    }                                                                      \
  }

  f32x4 acc[4];
#pragma unroll
  for (int t = 0; t < 4; ++t) acc[t] = (f32x4){0.f, 0.f, 0.f, 0.f};

  // prologue: stage round 0 (overwrites dead sow region)
  LOADR(0)
  WRITES()
  __syncthreads();

#pragma unroll 1
  for (int rho = 0; rho < 4; ++rho) {
    // issue next round's loads early (latency hides under tap loop)
    if (rho < 3) LOADR(rho + 1)

    const short* wfr = wf + ((size_t)(rho * 5 * 4) * 64 + lane) * 8;
    const char*  sbo = sxb + oct * 16;              // octet byte offset

    // tap-0 corner prefetch (ping-pong "next" set)
    uint4v nA, nB, nC, nD;
    {
      const char* pb_ = sbo + qsite[0] * SSTR;
      nA = *(const uint4v*)(pb_);
      nC = *(const uint4v*)(pb_ + SSTR);
      nD = *(const uint4v*)(pb_ + 70 * SSTR);
      nB = *(const uint4v*)(pb_ + 71 * SSTR);
    }

#define TAPBODY(J)                                                          \
    {                                                                       \
      /* A-frags for THIS tap: issued ~full-body ahead of their MFMA use */ \
      const short* wfb_ = wfr + (size_t)(J) * 4 * 64 * 8;                   \
      const short8v af0 = *(const short8v*)(wfb_);                          \
      const short8v af1 = *(const short8v*)(wfb_ + 1 * 64 * 8);             \
      const short8v af2 = *(const short8v*)(wfb_ + 2 * 64 * 8);             \
      const short8v af3 = *(const short8v*)(wfb_ + 3 * 64 * 8);             \
      const uint4v A = nA, B = nB, C = nC, D = nD;                          \
      if ((J) < 4) {  /* prefetch NEXT tap's corners (idx clamped: dead     \
                         arm at J=4 must still be in-bounds) */             \
        const char* pb_ = sbo + qsite[(J) < 4 ? (J) + 1 : 0] * SSTR;        \
        nA = *(const uint4v*)(pb_);                                         \
        nC = *(const uint4v*)(pb_ + SSTR);                                  \
        nD = *(const uint4v*)(pb_ + 70 * SSTR);                             \
        nB = *(const uint4v*)(pb_ + 71 * SSTR);                             \
      }                                                                     \
      short8v bfr;                                                          \
      if (__all((inwm >> (J)) & 1)) {                                       \
        const float wxl = qwx[J], wyl = qwy[J];                             \
        const float wxr = 1.f - wxl, wyr = 1.f - wyl;                       \
        const float g0 = wxl * wyl, g1 = wxr * wyr;                         \
        const float g2 = wxl * wyr, g3 = wxr * wyl;                         \
        uint4v bw;                                                          \
        _Pragma("unroll")                                                   \
        for (int m = 0; m < 4; ++m) {                                       \
          const float alo = __uint_as_float(A[m] << 16);                    \
          const float ahi = __uint_as_float(A[m] & 0xFFFF0000u);            \
          const float blo = __uint_as_float(B[m] << 16);                    \
          const float bhi = __uint_as_float(B[m] & 0xFFFF0000u);            \
          const float clo = __uint_as_float(C[m] << 16);                    \
          const float chi = __uint_as_float(C[m] & 0xFFFF0000u);            \
          const float dlo = __uint_as_float(D[m] << 16);                    \
          const float dhi = __uint_as_float(D[m] & 0xFFFF0000u);            \
          float sl = g0 * alo;                                              \
          sl = fmaf(g1, blo, sl); sl = fmaf(g2, clo, sl);                   \
          sl = fmaf(g3, dlo, sl);                                           \
          float sh = g0 * ahi;                                              \
          sh = fmaf(g1, bhi, sh); sh = fmaf(g2, chi, sh);                   \
          sh = fmaf(g3, dhi, sh);                                           \
          bw[m] = cvt_pk_bf16(sl, sh);                                      \
        }                                                                   \
        bfr = __builtin_bit_cast(short8v, bw);                              \
      } else {                                                              \
        /* fallback: exact-original-math global fp32 gather for this tap */ \
        const int  n9_  = 2 * (J) + half;                                   \
        const bool pad_ = (n9_ >= 9);                                       \
        const int  n_   = pad_ ? 0 : n9_;                                   \
        const float ox_ = sOffT[n_ * 64 + rr];                              \
        const float oy_ = sOffT[(9 + n_) * 64 + rr];                        \
        const float px_ = (float)(c0 + (n_ % 3)) + ox_;                     \
        const float py_ = (float)(r + (n_ / 3)) + oy_;                      \
        const float fx_ = floorf(px_);                                      \
        const float fy_ = floorf(py_);                                      \
        int ltx_ = (int)fx_, lty_ = (int)fy_;                               \
        int rbx_ = ltx_ + 1, rby_ = lty_ + 1;                               \
        ltx_ = min(max(ltx_, 0), HW + 1); lty_ = min(max(lty_, 0), HW + 1); \
        rbx_ = min(max(rbx_, 0), HW + 1); rby_ = min(max(rby_, 0), HW + 1); \
        const float pxc_ = fminf(fmaxf(px_, 0.f), (float)(HW + 1));         \
        const float pyc_ = fminf(fmaxf(py_, 0.f), (float)(HW + 1));         \
        const float wxl_ = 1.f + (float)ltx_ - pxc_;                        \
        const float wxr_ = 1.f - ((float)rbx_ - pxc_);                      \
        const float wyl_ = 1.f + (float)lty_ - pyc_;                        \
        const float wyr_ = 1.f - ((float)rby_ - pyc_);                      \
        const int   cxs_[4] = { ltx_, rbx_, ltx_, rbx_ };                   \
        const int   cys_[4] = { lty_, rby_, rby_, lty_ };                   \
        const float cgs_[4] = { wxl_ * wyl_, wxr_ * wyr_,                   \
                                wxl_ * wyr_, wxr_ * wyl_ };                 \
        int gi_[4]; float gw_[4];                                           \
        _Pragma("unroll")                                                   \
        for (int k = 0; k < 4; ++k) {                                       \
          const bool ok_ = (cxs_[k] >= 1) & (cxs_[k] <= HW) &               \
                           (cys_[k] >= 1) & (cys_[k] <= HW);                \
          gi_[k] = ok_ ? ((cxs_[k] - 1) * HW + (cys_[k] - 1)) : 0;          \
          gw_[k] = (ok_ && !pad_) ? cgs_[k] : 0.f;                          \
        }                                                                   \
        const float* xpl_ = xb + (size_t)(rho * 16 + oct * 8) * HW2;        \
        _Pragma("unroll")                                                   \
        for (int e = 0; e < 8; ++e) {                                       \
          const float* xe_ = xpl_ + (size_t)e * HW2;                        \
          float sv_ = gw_[0] * xe_[gi_[0]];                                 \
          sv_ = fmaf(gw_[1], xe_[gi_[1]], sv_);                             \
          sv_ = fmaf(gw_[2], xe_[gi_[2]], sv_);                             \
          sv_ = fmaf(gw_[3], xe_[gi_[3]], sv_);                             \
          bfr[e] = (short)f2bf(sv_);                                        \
        }                                                                   \
      }                                                                     \
      acc[0] = __builtin_amdgcn_mfma_f32_16x16x32_bf16(af0, bfr, acc[0], 0, 0, 0); \
      acc[1] = __builtin_amdgcn_mfma_f32_16x16x32_bf16(af1, bfr, acc[1], 0, 0, 0); \
      acc[2] = __builtin_amdgcn_mfma_f32_16x16x32_bf16(af2, bfr, acc[2], 0, 0, 0); \
      acc[3] = __builtin_amdgcn_mfma_f32_16x16x32_bf16(af3, bfr, acc[3], 0, 0, 0); \
    }

    TAPBODY(0) TAPBODY(1) TAPBODY(2) TAPBODY(3) TAPBODY(4)
#undef TAPBODY

    __syncthreads();                                // window free to overwrite
    if (rho < 3) {
      WRITES()
      __syncthreads();                              // window ready for rho+1
    }
  }

  // C/D store (R2-verified): col = i = pixel, row(oc) = t*16 + a*4 + jj.
#pragma unroll
  for (int t = 0; t < 4; ++t)
#pragma unroll
    for (int jj = 0; jj < 4; ++jj) {
      const int oc = t * 16 + a * 4 + jj;
      out[((size_t)(b * COUT + oc)) * HW2 + (size_t)r * HW + c0] = acc[t][jj];
    }
#undef LOADR
#undef WRITES
}

// ---------------------------------------------------------------------------
extern "C" void kernel_launch(void* const* d_in, const int* in_sizes, int n_in,
                              void* d_out, int out_size, void* d_ws, size_t ws_size,
                              hipStream_t stream) {
  const float* x  = (const float*)d_in[0];   // (2,64,256,256)
  const float* pw = (const float*)d_in[1];   // (18,64,3,3)
  const float* pb = (const float*)d_in[2];   // (18,)
  const float* w  = (const float*)d_in[3];   // (64,64,3,3)
  float* out = (float*)d_out;                // (2,64,256,256)

  char* wsb = (char*)d_ws;
  short* wfg = (short*)wsb;                  // 81,920 B
  short* wf2 = (short*)(wsb + 81920);        // 40,960 B

  wfrag_kernel<<<30, 256, 0, stream>>>(w, pw, wfg, wf2);
  dim3 grid(1024, 2);
  fused_kernel<<<grid, 256, 0, stream>>>(x, wfg, wf2, pb, out);
}

// Round 18
// 164.100 us; speedup vs baseline: 1.0637x; 1.0637x over previous
//
#include <hip/hip_runtime.h>

#define HW   256
#define HW2  (HW * HW)
#define CIN  64
#define COUT 64

#define RXN   7              // deform window rows: padded row coords c0-2 .. c0+4
#define CYN   70             // deform window cols: padded col coords r0-2 .. r0+67
#define NSITE (RXN * CYN)    // 490
#define SSTR  48             // bytes/site: 16 bf16 planes (32B) + 16B pad; 16-aligned

#define ONS   198            // offs window sites: 66 rows x 3 cols
#define OSTR  144            // bytes/site: 64 bf16 planes + 16B pad; 16-aligned

typedef __attribute__((ext_vector_type(8))) short    short8v;   // 8 bf16
typedef __attribute__((ext_vector_type(4))) float    f32x4;
typedef __attribute__((ext_vector_type(4))) unsigned uint4v;

__device__ __forceinline__ unsigned short f2bf(float f) {      // RNE fp32->bf16
  unsigned u = __float_as_uint(f);
  u = u + 0x7FFFu + ((u >> 16) & 1u);
  return (unsigned short)(u >> 16);
}
__device__ __forceinline__ unsigned cvt_pk_bf16(float lo, float hi) {
  unsigned r;                                        // {hi16: bf16(hi), lo16: bf16(lo)}
  asm("v_cvt_pk_bf16_f32 %0, %1, %2" : "=v"(r) : "v"(lo), "v"(hi));
  return r;
}

// ---------------------------------------------------------------------------
// Kernel W (verified R8/R12, unchanged): deform weights wf (bf16) +
// offs weights wf2 (bf16), tap-pair fragment order.
// ---------------------------------------------------------------------------
__global__ void wfrag_kernel(const float* __restrict__ w, const float* __restrict__ pw,
                             short* __restrict__ wf, short* __restrict__ wf2) {
  const int T = blockIdx.x * 256 + threadIdx.x;      // 5120 + 2560 fragments
  if (T < 5120) {
    const int l    = T & 63;
    const int t    = (T >> 6) & 3;
    const int g    = T >> 8;                         // rho*5 + j
    const int j    = g % 5;
    const int rho  = g / 5;
    const int half = (l >> 5) & 1;
    const int oct  = (l >> 4) & 1;
    const int n    = 2 * j + half;
    const int oc   = t * 16 + (l & 15);
    const int ic0  = rho * 16 + oct * 8;
    short8v v;
#pragma unroll
    for (int e = 0; e < 8; ++e)
      v[e] = (n < 9) ? (short)f2bf(w[(oc * CIN + ic0 + e) * 9 + n]) : (short)0;
    *(short8v*)(wf + (size_t)T * 8) = v;
  } else if (T < 7680) {
    const int T2   = T - 5120;
    const int l    = T2 & 63;
    const int t    = (T2 >> 6) & 1;
    const int g    = T2 >> 7;                        // rho*5 + j
    const int j    = g % 5;
    const int rho  = g / 5;
    const int half = (l >> 5) & 1;
    const int oct  = (l >> 4) & 1;
    const int n    = 2 * j + half;
    const int oc   = t * 16 + (l & 15);
    const int ic0  = rho * 16 + oct * 8;
    short8v v;
#pragma unroll
    for (int e = 0; e < 8; ++e)
      v[e] = (n < 9 && oc < 18) ? (short)f2bf(pw[(oc * CIN + ic0 + e) * 9 + n])
                                : (short)0;
    *(short8v*)(wf2 + (size_t)T2 * 8) = v;
  }
}

// ---------------------------------------------------------------------------
// Kernel A: offset conv via MFMA (verified R8, unchanged).
// Store layout off[b][c][ch][r].
// ---------------------------------------------------------------------------
__global__ __launch_bounds__(256) void offs_mfma_kernel(
    const float* __restrict__ x, const short* __restrict__ wf2,
    const float* __restrict__ pb, float* __restrict__ off)
{
  __shared__ __align__(16) char sow[ONS * OSTR];     // 28,512 B

  const int b    = blockIdx.y;
  const int bx   = blockIdx.x;                       // 4 r-tiles * 256 cols
  const int r0   = (bx & 3) * 64;
  const int c0   = bx >> 2;
  const int tid  = threadIdx.x;
  const int lane = tid & 63;
  const int i    = lane & 15;
  const int g4   = lane >> 4;                        // oct = g4&1, half = g4>>1
  const int oct  = g4 & 1;
  const int half = g4 >> 1;
  const int wv   = tid >> 6;
  const int r    = r0 + wv * 16 + i;

  // ---- stage 64 planes of the 66x3 window (zeros outside image) ----------
  if (tid < ONS) {
    const int rl = tid / 3, kw = tid - rl * 3;
    const int rr = r0 - 1 + rl;                      // image row
    const int cc = c0 - 1 + kw;                      // image col
    const bool ok = (rr >= 0) & (rr < HW) & (cc >= 0) & (cc < HW);
    const float* xq = x + (size_t)b * CIN * HW2
                    + (size_t)max(rr, 0) * HW + max(cc, 0);
    char* dst = sow + tid * OSTR;
#pragma unroll
    for (int m8 = 0; m8 < 8; ++m8) {
      uint4v v;
#pragma unroll
      for (int mm = 0; mm < 4; ++mm) {
        const int pl = m8 * 8 + mm * 2;
        const float v0 = ok ? xq[(size_t)pl * HW2] : 0.f;
        const float v1 = ok ? xq[(size_t)(pl + 1) * HW2] : 0.f;
        v[mm] = cvt_pk_bf16(v0, v1);
      }
      *(uint4v*)(dst + m8 * 16) = v;
    }
  }
  __syncthreads();

  f32x4 acc0 = (f32x4){0.f, 0.f, 0.f, 0.f};
  f32x4 acc1 = (f32x4){0.f, 0.f, 0.f, 0.f};

#pragma unroll
  for (int rho = 0; rho < 4; ++rho) {
#pragma unroll
    for (int j = 0; j < 5; ++j) {
      const int n  = 2 * j + half;
      const int nn = (n < 9) ? n : 0;                // tap 9: zero A-weights
      const int kh = nn / 3, kw = nn - kh * 3;
      const int site = (wv * 16 + i + kh) * 3 + kw;
      const short8v bfr = *(const short8v*)(sow + site * OSTR + rho * 32 + oct * 16);
      const short* wfb = wf2 + ((size_t)(((rho * 5 + j) * 2) * 64) + lane) * 8;
      const short8v a0 = *(const short8v*)(wfb);
      const short8v a1 = *(const short8v*)(wfb + 64 * 8);
      acc0 = __builtin_amdgcn_mfma_f32_16x16x32_bf16(a0, bfr, acc0, 0, 0, 0);
      acc1 = __builtin_amdgcn_mfma_f32_16x16x32_bf16(a1, bfr, acc1, 0, 0, 0);
    }
  }

  // store: ch = t*16 + g4*4 + jj (C/D row), pixel = r (col). ch<18 only.
  float* ob = off + (size_t)(b * HW + c0) * 18 * HW;
#pragma unroll
  for (int jj = 0; jj < 4; ++jj) {
    const int ch = g4 * 4 + jj;                      // t=0: 0..15
    ob[(size_t)ch * HW + r] = acc0[jj] + pb[ch];
  }
  if (g4 == 0) {
#pragma unroll
    for (int jj = 0; jj < 2; ++jj) {
      const int ch = 16 + jj;                        // t=1: 16,17
      ob[(size_t)ch * HW + r] = acc1[jj] + pb[ch];
    }
  }
}

// ---------------------------------------------------------------------------
// Kernel B: deform (verified R12). T14 staging split + tap ping-pong +
// amdgpu_waves_per_eu(2,4) (VGPR 116, no spill). Numerics = R8/R12.
// ---------------------------------------------------------------------------
__global__ __launch_bounds__(256)
__attribute__((amdgpu_waves_per_eu(2, 4)))
void deform_kernel(
    const float* __restrict__ x, const float* __restrict__ off,
    const short* __restrict__ wf, float* __restrict__ out)
{
  __shared__ __align__(16) char sxb[NSITE * SSTR];   // 23,520 B

  const int b    = blockIdx.y;
  const int bx   = blockIdx.x;                       // 4 r-tiles * 256 cols
  const int r0   = (bx & 3) * 64;
  const int c0   = bx >> 2;
  const int tid  = threadIdx.x;
  const int lane = tid & 63;
  const int i    = lane & 15;
  const int a    = (lane >> 4) & 3;
  const int oct  = a & 1;
  const int half = a >> 1;
  const int wv   = tid >> 6;
  const int r    = r0 + wv * 16 + i;                 // this thread's pixel row

  // ---- corner tables: 1 site + (wxl,wyl) per tap (verified R8) -----------
  unsigned qsite[5];
  float    qwx[5], qwy[5];
  unsigned inwm = 0;
  const float* obp = off + (size_t)(b * HW + c0) * 18 * HW;
#pragma unroll
  for (int t5 = 0; t5 < 5; ++t5) {
    const int  n9  = 2 * t5 + half;
    const bool pad = (n9 >= 9);
    const int  n   = pad ? 0 : n9;
    const float ox = obp[(size_t)n * HW + r];
    const float oy = obp[(size_t)(9 + n) * HW + r];
    const float px = (float)(c0 + (n % 3)) + ox;     // transposed base: row ~ c
    const float py = (float)(r + (n / 3)) + oy;      // col ~ r
    const float fx = floorf(px);
    const float fy = floorf(py);
    const int ltx = (int)fx, lty = (int)fy;
    const bool okc = (ltx >= 0) & (lty >= 0) & (ltx + 1 <= HW + 1) & (lty + 1 <= HW + 1);
    const int lx = ltx - c0 + 2;                     // window-local row
    const int ly = lty - r0 + 2;                     // window-local col
    const bool inw = okc & (lx >= 0) & (lx <= RXN - 2) & (ly >= 0) & (ly <= CYN - 2);
    qsite[t5] = (pad || !inw) ? 0u : (unsigned)(lx * CYN + ly);
    qwx[t5]   = 1.f + fx - px;                       // wxl (exact in fast path)
    qwy[t5]   = 1.f + fy - py;                       // wyl
    inwm |= ((inw || pad) ? 1u : 0u) << t5;
  }

  // ---- staging site descriptors (sites tid and tid+256) ------------------
  const int s1 = tid, s2 = tid + 256;
  int gi1 = 0, gi2 = 0; bool ok1, ok2;
  {
    const int rxl = s1 / CYN, cyl = s1 - rxl * CYN;
    const int rx = c0 - 2 + rxl, cyp = r0 - 2 + cyl;
    ok1 = (rx >= 1) & (rx <= HW) & (cyp >= 1) & (cyp <= HW);
    if (ok1) gi1 = (rx - 1) * HW + (cyp - 1);
  }
  {
    const int rxl = s2 / CYN, cyl = s2 - rxl * CYN;
    const int rx = c0 - 2 + rxl, cyp = r0 - 2 + cyl;
    ok2 = (s2 < NSITE) & (rx >= 1) & (rx <= HW) & (cyp >= 1) & (cyp <= HW);
    if (ok2) gi2 = (rx - 1) * HW + (cyp - 1);
  }

  const float* xb = x + (size_t)b * CIN * HW2;

  // ---- T14 pipeline registers: round's 32 staging floats -----------------
  float pv1[16], pv2[16];

#define LOADR(RHO)                                                         \
  {                                                                        \
    const float* xsrc = xb + (size_t)((RHO) * 16) * HW2;                   \
    _Pragma("unroll")                                                      \
    for (int m = 0; m < 16; ++m) {                                         \
      const float* xp = xsrc + (size_t)m * HW2;                            \
      pv1[m] = ok1 ? xp[gi1] : 0.f;                                        \
      pv2[m] = ok2 ? xp[gi2] : 0.f;                                        \
    }                                                                      \
  }

#define WRITES()                                                           \
  {                                                                        \
    uint4v w0, w1;                                                         \
    _Pragma("unroll")                                                      \
    for (int m = 0; m < 4; ++m) w0[m] = cvt_pk_bf16(pv1[2*m], pv1[2*m+1]); \
    _Pragma("unroll")                                                      \
    for (int m = 0; m < 4; ++m) w1[m] = cvt_pk_bf16(pv1[8+2*m], pv1[9+2*m]);\
    *(uint4v*)(sxb + s1 * SSTR)      = w0;                                 \
    *(uint4v*)(sxb + s1 * SSTR + 16) = w1;                                 \
    if (s2 < NSITE) {                                                      \
      uint4v u0, u1;                                                       \
      _Pragma("unroll")                                                    \
      for (int m = 0; m < 4; ++m) u0[m] = cvt_pk_bf16(pv2[2*m], pv2[2*m+1]);\
      _Pragma("unroll")                                                    \
      for (int m = 0; m < 4; ++m) u1[m] = cvt_pk_bf16(pv2[8+2*m], pv2[9+2*m]);\
      *(uint4v*)(sxb + s2 * SSTR)      = u0;                               \
      *(uint4v*)(sxb + s2 * SSTR + 16) = u1;                               \
    }                                                                      \
  }

  f32x4 acc[4];
#pragma unroll
  for (int t = 0; t < 4; ++t) acc[t] = (f32x4){0.f, 0.f, 0.f, 0.f};

  // prologue: stage round 0
  LOADR(0)
  WRITES()
  __syncthreads();

#pragma unroll 1
  for (int rho = 0; rho < 4; ++rho) {
    // issue next round's loads early (latency hides under tap loop)
    if (rho < 3) LOADR(rho + 1)

    const short* wfr = wf + ((size_t)(rho * 5 * 4) * 64 + lane) * 8;
    const char*  sbo = sxb + oct * 16;               // octet byte offset

    // tap-0 corner prefetch (ping-pong "next" set)
    uint4v nA, nB, nC, nD;
    {
      const char* pb_ = sbo + qsite[0] * SSTR;
      nA = *(const uint4v*)(pb_);
      nC = *(const uint4v*)(pb_ + SSTR);
      nD = *(const uint4v*)(pb_ + 70 * SSTR);
      nB = *(const uint4v*)(pb_ + 71 * SSTR);
    }

#define TAPBODY(J)                                                          \
    {                                                                       \
      /* A-frags for THIS tap: issued ~full-body ahead of their MFMA use */ \
      const short* wfb_ = wfr + (size_t)(J) * 4 * 64 * 8;                   \
      const short8v af0 = *(const short8v*)(wfb_);                          \
      const short8v af1 = *(const short8v*)(wfb_ + 1 * 64 * 8);             \
      const short8v af2 = *(const short8v*)(wfb_ + 2 * 64 * 8);             \
      const short8v af3 = *(const short8v*)(wfb_ + 3 * 64 * 8);             \
      const uint4v A = nA, B = nB, C = nC, D = nD;                          \
      if ((J) < 4) {  /* prefetch NEXT tap's corners (idx clamped: dead     \
                         arm at J=4 must still be in-bounds) */             \
        const char* pb_ = sbo + qsite[(J) < 4 ? (J) + 1 : 0] * SSTR;        \
        nA = *(const uint4v*)(pb_);                                         \
        nC = *(const uint4v*)(pb_ + SSTR);                                  \
        nD = *(const uint4v*)(pb_ + 70 * SSTR);                             \
        nB = *(const uint4v*)(pb_ + 71 * SSTR);                             \
      }                                                                     \
      short8v bfr;                                                          \
      if (__all((inwm >> (J)) & 1)) {                                       \
        const float wxl = qwx[J], wyl = qwy[J];                             \
        const float wxr = 1.f - wxl, wyr = 1.f - wyl;                       \
        const float g0 = wxl * wyl, g1 = wxr * wyr;                         \
        const float g2 = wxl * wyr, g3 = wxr * wyl;                         \
        uint4v bw;                                                          \
        _Pragma("unroll")                                                   \
        for (int m = 0; m < 4; ++m) {                                       \
          const float alo = __uint_as_float(A[m] << 16);                    \
          const float ahi = __uint_as_float(A[m] & 0xFFFF0000u);            \
          const float blo = __uint_as_float(B[m] << 16);                    \
          const float bhi = __uint_as_float(B[m] & 0xFFFF0000u);            \
          const float clo = __uint_as_float(C[m] << 16);                    \
          const float chi = __uint_as_float(C[m] & 0xFFFF0000u);            \
          const float dlo = __uint_as_float(D[m] << 16);                    \
          const float dhi = __uint_as_float(D[m] & 0xFFFF0000u);            \
          float sl = g0 * alo;                                              \
          sl = fmaf(g1, blo, sl); sl = fmaf(g2, clo, sl);                   \
          sl = fmaf(g3, dlo, sl);                                           \
          float sh = g0 * ahi;                                              \
          sh = fmaf(g1, bhi, sh); sh = fmaf(g2, chi, sh);                   \
          sh = fmaf(g3, dhi, sh);                                           \
          bw[m] = cvt_pk_bf16(sl, sh);                                      \
        }                                                                   \
        bfr = __builtin_bit_cast(short8v, bw);                              \
      } else {                                                              \
        /* fallback: exact-original-math global fp32 gather for this tap */ \
        const int  n9_  = 2 * (J) + half;                                   \
        const bool pad_ = (n9_ >= 9);                                       \
        const int  n_   = pad_ ? 0 : n9_;                                   \
        const float ox_ = obp[(size_t)n_ * HW + r];                         \
        const float oy_ = obp[(size_t)(9 + n_) * HW + r];                   \
        const float px_ = (float)(c0 + (n_ % 3)) + ox_;                     \
        const float py_ = (float)(r + (n_ / 3)) + oy_;                      \
        const float fx_ = floorf(px_);                                      \
        const float fy_ = floorf(py_);                                      \
        int ltx_ = (int)fx_, lty_ = (int)fy_;                               \
        int rbx_ = ltx_ + 1, rby_ = lty_ + 1;                               \
        ltx_ = min(max(ltx_, 0), HW + 1); lty_ = min(max(lty_, 0), HW + 1); \
        rbx_ = min(max(rbx_, 0), HW + 1); rby_ = min(max(rby_, 0), HW + 1); \
        const float pxc_ = fminf(fmaxf(px_, 0.f), (float)(HW + 1));         \
        const float pyc_ = fminf(fmaxf(py_, 0.f), (float)(HW + 1));         \
        const float wxl_ = 1.f + (float)ltx_ - pxc_;                        \
        const float wxr_ = 1.f - ((float)rbx_ - pxc_);                      \
        const float wyl_ = 1.f + (float)lty_ - pyc_;                        \
        const float wyr_ = 1.f - ((float)rby_ - pyc_);                      \
        const int   cxs_[4] = { ltx_, rbx_, ltx_, rbx_ };                   \
        const int   cys_[4] = { lty_, rby_, rby_, lty_ };                   \
        const float cgs_[4] = { wxl_ * wyl_, wxr_ * wyr_,                   \
                                wxl_ * wyr_, wxr_ * wyl_ };                 \
        int gi_[4]; float gw_[4];                                           \
        _Pragma("unroll")                                                   \
        for (int k = 0; k < 4; ++k) {                                       \
          const bool ok_ = (cxs_[k] >= 1) & (cxs_[k] <= HW) &               \
                           (cys_[k] >= 1) & (cys_[k] <= HW);                \
          gi_[k] = ok_ ? ((cxs_[k] - 1) * HW + (cys_[k] - 1)) : 0;          \
          gw_[k] = (ok_ && !pad_) ? cgs_[k] : 0.f;                          \
        }                                                                   \
        const float* xpl_ = xb + (size_t)(rho * 16 + oct * 8) * HW2;        \
        _Pragma("unroll")                                                   \
        for (int e = 0; e < 8; ++e) {                                       \
          const float* xe_ = xpl_ + (size_t)e * HW2;                        \
          float sv_ = gw_[0] * xe_[gi_[0]];                                 \
          sv_ = fmaf(gw_[1], xe_[gi_[1]], sv_);                             \
          sv_ = fmaf(gw_[2], xe_[gi_[2]], sv_);                             \
          sv_ = fmaf(gw_[3], xe_[gi_[3]], sv_);                             \
          bfr[e] = (short)f2bf(sv_);                                        \
        }                                                                   \
      }                                                                     \
      acc[0] = __builtin_amdgcn_mfma_f32_16x16x32_bf16(af0, bfr, acc[0], 0, 0, 0); \
      acc[1] = __builtin_amdgcn_mfma_f32_16x16x32_bf16(af1, bfr, acc[1], 0, 0, 0); \
      acc[2] = __builtin_amdgcn_mfma_f32_16x16x32_bf16(af2, bfr, acc[2], 0, 0, 0); \
      acc[3] = __builtin_amdgcn_mfma_f32_16x16x32_bf16(af3, bfr, acc[3], 0, 0, 0); \
    }

    TAPBODY(0) TAPBODY(1) TAPBODY(2) TAPBODY(3) TAPBODY(4)
#undef TAPBODY

    __syncthreads();                                 // window free to overwrite
    if (rho < 3) {
      WRITES()
      __syncthreads();                               // window ready for rho+1
    }
  }

  // C/D store (R2-verified): col = i = pixel, row(oc) = t*16 + a*4 + jj.
#pragma unroll
  for (int t = 0; t < 4; ++t)
#pragma unroll
    for (int jj = 0; jj < 4; ++jj) {
      const int oc = t * 16 + a * 4 + jj;
      out[((size_t)(b * COUT + oc)) * HW2 + (size_t)r * HW + c0] = acc[t][jj];
    }
#undef LOADR
#undef WRITES
}

// ---------------------------------------------------------------------------
extern "C" void kernel_launch(void* const* d_in, const int* in_sizes, int n_in,
                              void* d_out, int out_size, void* d_ws, size_t ws_size,
                              hipStream_t stream) {
  const float* x  = (const float*)d_in[0];   // (2,64,256,256)
  const float* pw = (const float*)d_in[1];   // (18,64,3,3)
  const float* pb = (const float*)d_in[2];   // (18,)
  const float* w  = (const float*)d_in[3];   // (64,64,3,3)
  float* out = (float*)d_out;                // (2,64,256,256)

  char* wsb = (char*)d_ws;
  float* off = (float*)wsb;                                  // 9,437,184 B
  short* wfg = (short*)(wsb + (size_t)2 * 18 * HW2 * 4);     // 81,920 B
  short* wf2 = (short*)(wsb + (size_t)2 * 18 * HW2 * 4 + 81920); // 40,960 B

  wfrag_kernel<<<30, 256, 0, stream>>>(w, pw, wfg, wf2);
  dim3 grid(1024, 2);
  offs_mfma_kernel<<<grid, 256, 0, stream>>>(x, wf2, pb, off);
  deform_kernel<<<grid, 256, 0, stream>>>(x, off, wfg, out);
}

// Round 19
// 164.062 us; speedup vs baseline: 1.0640x; 1.0002x over previous
//
#include <hip/hip_runtime.h>

#define HW   256
#define HW2  (HW * HW)
#define CIN  64
#define COUT 64

#define RXN   7              // deform window rows: padded row coords c0-2 .. c0+4
#define CYN   70             // deform window cols: padded col coords r0-2 .. r0+67
#define NSITE (RXN * CYN)    // 490
#define SSTR  48             // bytes/site: 16 bf16 planes (32B) + 16B pad; 16-aligned

#define ONS   198            // offs window sites: 66 rows x 3 cols
#define OSTR  144            // bytes/site: 64 bf16 planes + 16B pad; 16-aligned

typedef __attribute__((ext_vector_type(8))) short    short8v;   // 8 bf16
typedef __attribute__((ext_vector_type(4))) float    f32x4;
typedef __attribute__((ext_vector_type(4))) unsigned uint4v;

__device__ __forceinline__ unsigned short f2bf(float f) {      // RNE fp32->bf16
  unsigned u = __float_as_uint(f);
  u = u + 0x7FFFu + ((u >> 16) & 1u);
  return (unsigned short)(u >> 16);
}
__device__ __forceinline__ unsigned cvt_pk_bf16(float lo, float hi) {
  unsigned r;                                        // {hi16: bf16(hi), lo16: bf16(lo)}
  asm("v_cvt_pk_bf16_f32 %0, %1, %2" : "=v"(r) : "v"(lo), "v"(hi));
  return r;
}

// ---------------------------------------------------------------------------
// Kernel W (verified R8/R12, unchanged): deform weights wf (bf16) +
// offs weights wf2 (bf16), tap-pair fragment order.
// ---------------------------------------------------------------------------
__global__ void wfrag_kernel(const float* __restrict__ w, const float* __restrict__ pw,
                             short* __restrict__ wf, short* __restrict__ wf2) {
  const int T = blockIdx.x * 256 + threadIdx.x;      // 5120 + 2560 fragments
  if (T < 5120) {
    const int l    = T & 63;
    const int t    = (T >> 6) & 3;
    const int g    = T >> 8;                         // rho*5 + j
    const int j    = g % 5;
    const int rho  = g / 5;
    const int half = (l >> 5) & 1;
    const int oct  = (l >> 4) & 1;
    const int n    = 2 * j + half;
    const int oc   = t * 16 + (l & 15);
    const int ic0  = rho * 16 + oct * 8;
    short8v v;
#pragma unroll
    for (int e = 0; e < 8; ++e)
      v[e] = (n < 9) ? (short)f2bf(w[(oc * CIN + ic0 + e) * 9 + n]) : (short)0;
    *(short8v*)(wf + (size_t)T * 8) = v;
  } else if (T < 7680) {
    const int T2   = T - 5120;
    const int l    = T2 & 63;
    const int t    = (T2 >> 6) & 1;
    const int g    = T2 >> 7;                        // rho*5 + j
    const int j    = g % 5;
    const int rho  = g / 5;
    const int half = (l >> 5) & 1;
    const int oct  = (l >> 4) & 1;
    const int n    = 2 * j + half;
    const int oc   = t * 16 + (l & 15);
    const int ic0  = rho * 16 + oct * 8;
    short8v v;
#pragma unroll
    for (int e = 0; e < 8; ++e)
      v[e] = (n < 9 && oc < 18) ? (short)f2bf(pw[(oc * CIN + ic0 + e) * 9 + n])
                                : (short)0;
    *(short8v*)(wf2 + (size_t)T2 * 8) = v;
  }
}

// ---------------------------------------------------------------------------
// Kernel A: offset conv via MFMA (verified R8, unchanged).
// Store layout off[b][c][ch][r].
// ---------------------------------------------------------------------------
__global__ __launch_bounds__(256) void offs_mfma_kernel(
    const float* __restrict__ x, const short* __restrict__ wf2,
    const float* __restrict__ pb, float* __restrict__ off)
{
  __shared__ __align__(16) char sow[ONS * OSTR];     // 28,512 B

  const int b    = blockIdx.y;
  const int bx   = blockIdx.x;                       // 4 r-tiles * 256 cols
  const int r0   = (bx & 3) * 64;
  const int c0   = bx >> 2;
  const int tid  = threadIdx.x;
  const int lane = tid & 63;
  const int i    = lane & 15;
  const int g4   = lane >> 4;                        // oct = g4&1, half = g4>>1
  const int oct  = g4 & 1;
  const int half = g4 >> 1;
  const int wv   = tid >> 6;
  const int r    = r0 + wv * 16 + i;

  // ---- stage 64 planes of the 66x3 window (zeros outside image) ----------
  if (tid < ONS) {
    const int rl = tid / 3, kw = tid - rl * 3;
    const int rr = r0 - 1 + rl;                      // image row
    const int cc = c0 - 1 + kw;                      // image col
    const bool ok = (rr >= 0) & (rr < HW) & (cc >= 0) & (cc < HW);
    const float* xq = x + (size_t)b * CIN * HW2
                    + (size_t)max(rr, 0) * HW + max(cc, 0);
    char* dst = sow + tid * OSTR;
#pragma unroll
    for (int m8 = 0; m8 < 8; ++m8) {
      uint4v v;
#pragma unroll
      for (int mm = 0; mm < 4; ++mm) {
        const int pl = m8 * 8 + mm * 2;
        const float v0 = ok ? xq[(size_t)pl * HW2] : 0.f;
        const float v1 = ok ? xq[(size_t)(pl + 1) * HW2] : 0.f;
        v[mm] = cvt_pk_bf16(v0, v1);
      }
      *(uint4v*)(dst + m8 * 16) = v;
    }
  }
  __syncthreads();

  f32x4 acc0 = (f32x4){0.f, 0.f, 0.f, 0.f};
  f32x4 acc1 = (f32x4){0.f, 0.f, 0.f, 0.f};

#pragma unroll
  for (int rho = 0; rho < 4; ++rho) {
#pragma unroll
    for (int j = 0; j < 5; ++j) {
      const int n  = 2 * j + half;
      const int nn = (n < 9) ? n : 0;                // tap 9: zero A-weights
      const int kh = nn / 3, kw = nn - kh * 3;
      const int site = (wv * 16 + i + kh) * 3 + kw;
      const short8v bfr = *(const short8v*)(sow + site * OSTR + rho * 32 + oct * 16);
      const short* wfb = wf2 + ((size_t)(((rho * 5 + j) * 2) * 64) + lane) * 8;
      const short8v a0 = *(const short8v*)(wfb);
      const short8v a1 = *(const short8v*)(wfb + 64 * 8);
      acc0 = __builtin_amdgcn_mfma_f32_16x16x32_bf16(a0, bfr, acc0, 0, 0, 0);
      acc1 = __builtin_amdgcn_mfma_f32_16x16x32_bf16(a1, bfr, acc1, 0, 0, 0);
    }
  }

  // store: ch = t*16 + g4*4 + jj (C/D row), pixel = r (col). ch<18 only.
  float* ob = off + (size_t)(b * HW + c0) * 18 * HW;
#pragma unroll
  for (int jj = 0; jj < 4; ++jj) {
    const int ch = g4 * 4 + jj;                      // t=0: 0..15
    ob[(size_t)ch * HW + r] = acc0[jj] + pb[ch];
  }
  if (g4 == 0) {
#pragma unroll
    for (int jj = 0; jj < 2; ++jj) {
      const int ch = 16 + jj;                        // t=1: 16,17
      ob[(size_t)ch * HW + r] = acc1[jj] + pb[ch];
    }
  }
}

// ---------------------------------------------------------------------------
// Kernel B: deform. R12 structure + A-frag ping-pong: tap j consumes A-frags
// prefetched during tap j-1 (covers the ~250cy L2 latency that previously
// only had ~140cy of VALU cover), and prefetches tap j+1's. +16 VGPR, paired
// with waves_per_eu(2,3) so the allocator takes 3 waves/EU instead of
// squeezing/spilling at 128. Numerics identical to R8/R12.
// ---------------------------------------------------------------------------
__global__ __launch_bounds__(256)
__attribute__((amdgpu_waves_per_eu(2, 3)))
void deform_kernel(
    const float* __restrict__ x, const float* __restrict__ off,
    const short* __restrict__ wf, float* __restrict__ out)
{
  __shared__ __align__(16) char sxb[NSITE * SSTR];   // 23,520 B

  const int b    = blockIdx.y;
  const int bx   = blockIdx.x;                       // 4 r-tiles * 256 cols
  const int r0   = (bx & 3) * 64;
  const int c0   = bx >> 2;
  const int tid  = threadIdx.x;
  const int lane = tid & 63;
  const int i    = lane & 15;
  const int a    = (lane >> 4) & 3;
  const int oct  = a & 1;
  const int half = a >> 1;
  const int wv   = tid >> 6;
  const int r    = r0 + wv * 16 + i;                 // this thread's pixel row

  // ---- corner tables: 1 site + (wxl,wyl) per tap (verified R8) -----------
  unsigned qsite[5];
  float    qwx[5], qwy[5];
  unsigned inwm = 0;
  const float* obp = off + (size_t)(b * HW + c0) * 18 * HW;
#pragma unroll
  for (int t5 = 0; t5 < 5; ++t5) {
    const int  n9  = 2 * t5 + half;
    const bool pad = (n9 >= 9);
    const int  n   = pad ? 0 : n9;
    const float ox = obp[(size_t)n * HW + r];
    const float oy = obp[(size_t)(9 + n) * HW + r];
    const float px = (float)(c0 + (n % 3)) + ox;     // transposed base: row ~ c
    const float py = (float)(r + (n / 3)) + oy;      // col ~ r
    const float fx = floorf(px);
    const float fy = floorf(py);
    const int ltx = (int)fx, lty = (int)fy;
    const bool okc = (ltx >= 0) & (lty >= 0) & (ltx + 1 <= HW + 1) & (lty + 1 <= HW + 1);
    const int lx = ltx - c0 + 2;                     // window-local row
    const int ly = lty - r0 + 2;                     // window-local col
    const bool inw = okc & (lx >= 0) & (lx <= RXN - 2) & (ly >= 0) & (ly <= CYN - 2);
    qsite[t5] = (pad || !inw) ? 0u : (unsigned)(lx * CYN + ly);
    qwx[t5]   = 1.f + fx - px;                       // wxl (exact in fast path)
    qwy[t5]   = 1.f + fy - py;                       // wyl
    inwm |= ((inw || pad) ? 1u : 0u) << t5;
  }

  // ---- staging site descriptors (sites tid and tid+256) ------------------
  const int s1 = tid, s2 = tid + 256;
  int gi1 = 0, gi2 = 0; bool ok1, ok2;
  {
    const int rxl = s1 / CYN, cyl = s1 - rxl * CYN;
    const int rx = c0 - 2 + rxl, cyp = r0 - 2 + cyl;
    ok1 = (rx >= 1) & (rx <= HW) & (cyp >= 1) & (cyp <= HW);
    if (ok1) gi1 = (rx - 1) * HW + (cyp - 1);
  }
  {
    const int rxl = s2 / CYN, cyl = s2 - rxl * CYN;
    const int rx = c0 - 2 + rxl, cyp = r0 - 2 + cyl;
    ok2 = (s2 < NSITE) & (rx >= 1) & (rx <= HW) & (cyp >= 1) & (cyp <= HW);
    if (ok2) gi2 = (rx - 1) * HW + (cyp - 1);
  }

  const float* xb = x + (size_t)b * CIN * HW2;

  // ---- T14 pipeline registers: round's 32 staging floats -----------------
  float pv1[16], pv2[16];

#define LOADR(RHO)                                                         \
  {                                                                        \
    const float* xsrc = xb + (size_t)((RHO) * 16) * HW2;                   \
    _Pragma("unroll")                                                      \
    for (int m = 0; m < 16; ++m) {                                         \
      const float* xp = xsrc + (size_t)m * HW2;                            \
      pv1[m] = ok1 ? xp[gi1] : 0.f;                                        \
      pv2[m] = ok2 ? xp[gi2] : 0.f;                                        \
    }                                                                      \
  }

#define WRITES()                                                           \
  {                                                                        \
    uint4v w0, w1;                                                         \
    _Pragma("unroll")                                                      \
    for (int m = 0; m < 4; ++m) w0[m] = cvt_pk_bf16(pv1[2*m], pv1[2*m+1]); \
    _Pragma("unroll")                                                      \
    for (int m = 0; m < 4; ++m) w1[m] = cvt_pk_bf16(pv1[8+2*m], pv1[9+2*m]);\
    *(uint4v*)(sxb + s1 * SSTR)      = w0;                                 \
    *(uint4v*)(sxb + s1 * SSTR + 16) = w1;                                 \
    if (s2 < NSITE) {                                                      \
      uint4v u0, u1;                                                       \
      _Pragma("unroll")                                                    \
      for (int m = 0; m < 4; ++m) u0[m] = cvt_pk_bf16(pv2[2*m], pv2[2*m+1]);\
      _Pragma("unroll")                                                    \
      for (int m = 0; m < 4; ++m) u1[m] = cvt_pk_bf16(pv2[8+2*m], pv2[9+2*m]);\
      *(uint4v*)(sxb + s2 * SSTR)      = u0;                               \
      *(uint4v*)(sxb + s2 * SSTR + 16) = u1;                               \
    }                                                                      \
  }

  f32x4 acc[4];
#pragma unroll
  for (int t = 0; t < 4; ++t) acc[t] = (f32x4){0.f, 0.f, 0.f, 0.f};

  // prologue: stage round 0
  LOADR(0)
  WRITES()
  __syncthreads();

#pragma unroll 1
  for (int rho = 0; rho < 4; ++rho) {
    // issue next round's loads early (latency hides under tap loop)
    if (rho < 3) LOADR(rho + 1)

    const short* wfr = wf + ((size_t)(rho * 5 * 4) * 64 + lane) * 8;
    const char*  sbo = sxb + oct * 16;               // octet byte offset

    // tap-0 prefetch: corners (LDS) AND A-frags (global) ping-pong sets
    uint4v nA, nB, nC, nD;
    short8v nf0, nf1, nf2, nf3;
    {
      const char* pb_ = sbo + qsite[0] * SSTR;
      nA = *(const uint4v*)(pb_);
      nC = *(const uint4v*)(pb_ + SSTR);
      nD = *(const uint4v*)(pb_ + 70 * SSTR);
      nB = *(const uint4v*)(pb_ + 71 * SSTR);
      nf0 = *(const short8v*)(wfr);
      nf1 = *(const short8v*)(wfr + 1 * 64 * 8);
      nf2 = *(const short8v*)(wfr + 2 * 64 * 8);
      nf3 = *(const short8v*)(wfr + 3 * 64 * 8);
    }

#define TAPBODY(J)                                                          \
    {                                                                       \
      const short8v af0 = nf0, af1 = nf1, af2 = nf2, af3 = nf3;             \
      const uint4v A = nA, B = nB, C = nC, D = nD;                          \
      if ((J) < 4) {  /* prefetch NEXT tap's corners + A-frags (idx         \
                         clamped: dead arm at J=4 must be in-bounds) */     \
        const char* pb_ = sbo + qsite[(J) < 4 ? (J) + 1 : 0] * SSTR;        \
        nA = *(const uint4v*)(pb_);                                         \
        nC = *(const uint4v*)(pb_ + SSTR);                                  \
        nD = *(const uint4v*)(pb_ + 70 * SSTR);                             \
        nB = *(const uint4v*)(pb_ + 71 * SSTR);                             \
        const short* wfb_ = wfr + (size_t)((J) + 1) * 4 * 64 * 8;           \
        nf0 = *(const short8v*)(wfb_);                                      \
        nf1 = *(const short8v*)(wfb_ + 1 * 64 * 8);                         \
        nf2 = *(const short8v*)(wfb_ + 2 * 64 * 8);                         \
        nf3 = *(const short8v*)(wfb_ + 3 * 64 * 8);                         \
      }                                                                     \
      short8v bfr;                                                          \
      if (__all((inwm >> (J)) & 1)) {                                       \
        const float wxl = qwx[J], wyl = qwy[J];                             \
        const float wxr = 1.f - wxl, wyr = 1.f - wyl;                       \
        const float g0 = wxl * wyl, g1 = wxr * wyr;                         \
        const float g2 = wxl * wyr, g3 = wxr * wyl;                         \
        uint4v bw;                                                          \
        _Pragma("unroll")                                                   \
        for (int m = 0; m < 4; ++m) {                                       \
          const float alo = __uint_as_float(A[m] << 16);                    \
          const float ahi = __uint_as_float(A[m] & 0xFFFF0000u);            \
          const float blo = __uint_as_float(B[m] << 16);                    \
          const float bhi = __uint_as_float(B[m] & 0xFFFF0000u);            \
          const float clo = __uint_as_float(C[m] << 16);                    \
          const float chi = __uint_as_float(C[m] & 0xFFFF0000u);            \
          const float dlo = __uint_as_float(D[m] << 16);                    \
          const float dhi = __uint_as_float(D[m] & 0xFFFF0000u);            \
          float sl = g0 * alo;                                              \
          sl = fmaf(g1, blo, sl); sl = fmaf(g2, clo, sl);                   \
          sl = fmaf(g3, dlo, sl);                                           \
          float sh = g0 * ahi;                                              \
          sh = fmaf(g1, bhi, sh); sh = fmaf(g2, chi, sh);                   \
          sh = fmaf(g3, dhi, sh);                                           \
          bw[m] = cvt_pk_bf16(sl, sh);                                      \
        }                                                                   \
        bfr = __builtin_bit_cast(short8v, bw);                              \
      } else {                                                              \
        /* fallback: exact-original-math global fp32 gather for this tap */ \
        const int  n9_  = 2 * (J) + half;                                   \
        const bool pad_ = (n9_ >= 9);                                       \
        const int  n_   = pad_ ? 0 : n9_;                                   \
        const float ox_ = obp[(size_t)n_ * HW + r];                         \
        const float oy_ = obp[(size_t)(9 + n_) * HW + r];                   \
        const float px_ = (float)(c0 + (n_ % 3)) + ox_;                     \
        const float py_ = (float)(r + (n_ / 3)) + oy_;                      \
        const float fx_ = floorf(px_);                                      \
        const float fy_ = floorf(py_);                                      \
        int ltx_ = (int)fx_, lty_ = (int)fy_;                               \
        int rbx_ = ltx_ + 1, rby_ = lty_ + 1;                               \
        ltx_ = min(max(ltx_, 0), HW + 1); lty_ = min(max(lty_, 0), HW + 1); \
        rbx_ = min(max(rbx_, 0), HW + 1); rby_ = min(max(rby_, 0), HW + 1); \
        const float pxc_ = fminf(fmaxf(px_, 0.f), (float)(HW + 1));         \
        const float pyc_ = fminf(fmaxf(py_, 0.f), (float)(HW + 1));         \
        const float wxl_ = 1.f + (float)ltx_ - pxc_;                        \
        const float wxr_ = 1.f - ((float)rbx_ - pxc_);                      \
        const float wyl_ = 1.f + (float)lty_ - pyc_;                        \
        const float wyr_ = 1.f - ((float)rby_ - pyc_);                      \
        const int   cxs_[4] = { ltx_, rbx_, ltx_, rbx_ };                   \
        const int   cys_[4] = { lty_, rby_, rby_, lty_ };                   \
        const float cgs_[4] = { wxl_ * wyl_, wxr_ * wyr_,                   \
                                wxl_ * wyr_, wxr_ * wyl_ };                 \
        int gi_[4]; float gw_[4];                                           \
        _Pragma("unroll")                                                   \
        for (int k = 0; k < 4; ++k) {                                       \
          const bool ok_ = (cxs_[k] >= 1) & (cxs_[k] <= HW) &               \
                           (cys_[k] >= 1) & (cys_[k] <= HW);                \
          gi_[k] = ok_ ? ((cxs_[k] - 1) * HW + (cys_[k] - 1)) : 0;          \
          gw_[k] = (ok_ && !pad_) ? cgs_[k] : 0.f;                          \
        }                                                                   \
        const float* xpl_ = xb + (size_t)(rho * 16 + oct * 8) * HW2;        \
        _Pragma("unroll")                                                   \
        for (int e = 0; e < 8; ++e) {                                       \
          const float* xe_ = xpl_ + (size_t)e * HW2;                        \
          float sv_ = gw_[0] * xe_[gi_[0]];                                 \
          sv_ = fmaf(gw_[1], xe_[gi_[1]], sv_);                             \
          sv_ = fmaf(gw_[2], xe_[gi_[2]], sv_);                             \
          sv_ = fmaf(gw_[3], xe_[gi_[3]], sv_);                             \
          bfr[e] = (short)f2bf(sv_);                                        \
        }                                                                   \
      }                                                                     \
      acc[0] = __builtin_amdgcn_mfma_f32_16x16x32_bf16(af0, bfr, acc[0], 0, 0, 0); \
      acc[1] = __builtin_amdgcn_mfma_f32_16x16x32_bf16(af1, bfr, acc[1], 0, 0, 0); \
      acc[2] = __builtin_amdgcn_mfma_f32_16x16x32_bf16(af2, bfr, acc[2], 0, 0, 0); \
      acc[3] = __builtin_amdgcn_mfma_f32_16x16x32_bf16(af3, bfr, acc[3], 0, 0, 0); \
    }

    TAPBODY(0) TAPBODY(1) TAPBODY(2) TAPBODY(3) TAPBODY(4)
#undef TAPBODY

    __syncthreads();                                 // window free to overwrite
    if (rho < 3) {
      WRITES()
      __syncthreads();                               // window ready for rho+1
    }
  }

  // C/D store (R2-verified): col = i = pixel, row(oc) = t*16 + a*4 + jj.
#pragma unroll
  for (int t = 0; t < 4; ++t)
#pragma unroll
    for (int jj = 0; jj < 4; ++jj) {
      const int oc = t * 16 + a * 4 + jj;
      out[((size_t)(b * COUT + oc)) * HW2 + (size_t)r * HW + c0] = acc[t][jj];
    }
#undef LOADR
#undef WRITES
}

// ---------------------------------------------------------------------------
extern "C" void kernel_launch(void* const* d_in, const int* in_sizes, int n_in,
                              void* d_out, int out_size, void* d_ws, size_t ws_size,
                              hipStream_t stream) {
  const float* x  = (const float*)d_in[0];   // (2,64,256,256)
  const float* pw = (const float*)d_in[1];   // (18,64,3,3)
  const float* pb = (const float*)d_in[2];   // (18,)
  const float* w  = (const float*)d_in[3];   // (64,64,3,3)
  float* out = (float*)d_out;                // (2,64,256,256)

  char* wsb = (char*)d_ws;
  float* off = (float*)wsb;                                  // 9,437,184 B
  short* wfg = (short*)(wsb + (size_t)2 * 18 * HW2 * 4);     // 81,920 B
  short* wf2 = (short*)(wsb + (size_t)2 * 18 * HW2 * 4 + 81920); // 40,960 B

  wfrag_kernel<<<30, 256, 0, stream>>>(w, pw, wfg, wf2);
  dim3 grid(1024, 2);
  offs_mfma_kernel<<<grid, 256, 0, stream>>>(x, wf2, pb, off);
  deform_kernel<<<grid, 256, 0, stream>>>(x, off, wfg, out);
}

// Round 20
// 161.756 us; speedup vs baseline: 1.0792x; 1.0143x over previous
//
#include <hip/hip_runtime.h>

#define HW   256
#define HW2  (HW * HW)
#define CIN  64
#define COUT 64

#define RXN   7              // deform window rows: padded row coords c0-2 .. c0+4
#define CYN   70             // deform window cols: padded col coords r0-2 .. r0+67
#define NSITE (RXN * CYN)    // 490
#define SSTR  48             // bytes/site: 16 bf16 planes (32B) + 16B pad; 16-aligned

#define ONS   198            // offs window sites: 66 rows x 3 cols
#define OSTR  144            // bytes/site: 64 bf16 planes + 16B pad; 16-aligned

typedef __attribute__((ext_vector_type(8))) short    short8v;   // 8 bf16
typedef __attribute__((ext_vector_type(4))) float    f32x4;
typedef __attribute__((ext_vector_type(4))) unsigned uint4v;

__device__ __forceinline__ unsigned short f2bf(float f) {      // RNE fp32->bf16
  unsigned u = __float_as_uint(f);
  u = u + 0x7FFFu + ((u >> 16) & 1u);
  return (unsigned short)(u >> 16);
}
__device__ __forceinline__ unsigned cvt_pk_bf16(float lo, float hi) {
  unsigned r;                                        // {hi16: bf16(hi), lo16: bf16(lo)}
  asm("v_cvt_pk_bf16_f32 %0, %1, %2" : "=v"(r) : "v"(lo), "v"(hi));
  return r;
}

// ---------------------------------------------------------------------------
// Kernel W (verified R8/R12, unchanged): deform weights wf (bf16) +
// offs weights wf2 (bf16), tap-pair fragment order.
// ---------------------------------------------------------------------------
__global__ void wfrag_kernel(const float* __restrict__ w, const float* __restrict__ pw,
                             short* __restrict__ wf, short* __restrict__ wf2) {
  const int T = blockIdx.x * 256 + threadIdx.x;      // 5120 + 2560 fragments
  if (T < 5120) {
    const int l    = T & 63;
    const int t    = (T >> 6) & 3;
    const int g    = T >> 8;                         // rho*5 + j
    const int j    = g % 5;
    const int rho  = g / 5;
    const int half = (l >> 5) & 1;
    const int oct  = (l >> 4) & 1;
    const int n    = 2 * j + half;
    const int oc   = t * 16 + (l & 15);
    const int ic0  = rho * 16 + oct * 8;
    short8v v;
#pragma unroll
    for (int e = 0; e < 8; ++e)
      v[e] = (n < 9) ? (short)f2bf(w[(oc * CIN + ic0 + e) * 9 + n]) : (short)0;
    *(short8v*)(wf + (size_t)T * 8) = v;
  } else if (T < 7680) {
    const int T2   = T - 5120;
    const int l    = T2 & 63;
    const int t    = (T2 >> 6) & 1;
    const int g    = T2 >> 7;                        // rho*5 + j
    const int j    = g % 5;
    const int rho  = g / 5;
    const int half = (l >> 5) & 1;
    const int oct  = (l >> 4) & 1;
    const int n    = 2 * j + half;
    const int oc   = t * 16 + (l & 15);
    const int ic0  = rho * 16 + oct * 8;
    short8v v;
#pragma unroll
    for (int e = 0; e < 8; ++e)
      v[e] = (n < 9 && oc < 18) ? (short)f2bf(pw[(oc * CIN + ic0 + e) * 9 + n])
                                : (short)0;
    *(short8v*)(wf2 + (size_t)T2 * 8) = v;
  }
}

// ---------------------------------------------------------------------------
// Kernel A: offset conv via MFMA (verified R8, unchanged).
// Store layout off[b][c][ch][r].
// ---------------------------------------------------------------------------
__global__ __launch_bounds__(256) void offs_mfma_kernel(
    const float* __restrict__ x, const short* __restrict__ wf2,
    const float* __restrict__ pb, float* __restrict__ off)
{
  __shared__ __align__(16) char sow[ONS * OSTR];     // 28,512 B

  const int b    = blockIdx.y;
  const int bx   = blockIdx.x;                       // 4 r-tiles * 256 cols
  const int r0   = (bx & 3) * 64;
  const int c0   = bx >> 2;
  const int tid  = threadIdx.x;
  const int lane = tid & 63;
  const int i    = lane & 15;
  const int g4   = lane >> 4;                        // oct = g4&1, half = g4>>1
  const int oct  = g4 & 1;
  const int half = g4 >> 1;
  const int wv   = tid >> 6;
  const int r    = r0 + wv * 16 + i;

  // ---- stage 64 planes of the 66x3 window (zeros outside image) ----------
  if (tid < ONS) {
    const int rl = tid / 3, kw = tid - rl * 3;
    const int rr = r0 - 1 + rl;                      // image row
    const int cc = c0 - 1 + kw;                      // image col
    const bool ok = (rr >= 0) & (rr < HW) & (cc >= 0) & (cc < HW);
    const float* xq = x + (size_t)b * CIN * HW2
                    + (size_t)max(rr, 0) * HW + max(cc, 0);
    char* dst = sow + tid * OSTR;
#pragma unroll
    for (int m8 = 0; m8 < 8; ++m8) {
      uint4v v;
#pragma unroll
      for (int mm = 0; mm < 4; ++mm) {
        const int pl = m8 * 8 + mm * 2;
        const float v0 = ok ? xq[(size_t)pl * HW2] : 0.f;
        const float v1 = ok ? xq[(size_t)(pl + 1) * HW2] : 0.f;
        v[mm] = cvt_pk_bf16(v0, v1);
      }
      *(uint4v*)(dst + m8 * 16) = v;
    }
  }
  __syncthreads();

  f32x4 acc0 = (f32x4){0.f, 0.f, 0.f, 0.f};
  f32x4 acc1 = (f32x4){0.f, 0.f, 0.f, 0.f};

#pragma unroll
  for (int rho = 0; rho < 4; ++rho) {
#pragma unroll
    for (int j = 0; j < 5; ++j) {
      const int n  = 2 * j + half;
      const int nn = (n < 9) ? n : 0;                // tap 9: zero A-weights
      const int kh = nn / 3, kw = nn - kh * 3;
      const int site = (wv * 16 + i + kh) * 3 + kw;
      const short8v bfr = *(const short8v*)(sow + site * OSTR + rho * 32 + oct * 16);
      const short* wfb = wf2 + ((size_t)(((rho * 5 + j) * 2) * 64) + lane) * 8;
      const short8v a0 = *(const short8v*)(wfb);
      const short8v a1 = *(const short8v*)(wfb + 64 * 8);
      acc0 = __builtin_amdgcn_mfma_f32_16x16x32_bf16(a0, bfr, acc0, 0, 0, 0);
      acc1 = __builtin_amdgcn_mfma_f32_16x16x32_bf16(a1, bfr, acc1, 0, 0, 0);
    }
  }

  // store: ch = t*16 + g4*4 + jj (C/D row), pixel = r (col). ch<18 only.
  float* ob = off + (size_t)(b * HW + c0) * 18 * HW;
#pragma unroll
  for (int jj = 0; jj < 4; ++jj) {
    const int ch = g4 * 4 + jj;                      // t=0: 0..15
    ob[(size_t)ch * HW + r] = acc0[jj] + pb[ch];
  }
  if (g4 == 0) {
#pragma unroll
    for (int jj = 0; jj < 2; ++jj) {
      const int ch = 16 + jj;                        // t=1: 16,17
      ob[(size_t)ch * HW + r] = acc1[jj] + pb[ch];
    }
  }
}

// ---------------------------------------------------------------------------
// Kernel B: deform (R18 structure, numerics = R8/R12) + T1 bijective XCD
// swizzle: logical bx = (hw_bx % 8) * 128 + hw_bx / 8, so each XCD owns a
// contiguous 128-block chunk. The 64 blocks sharing each 16-column output
// line-group then live on ONE XCD's L2, merging their 4B/line partial writes
// before write-back (measured 2.6x WRITE amplification = cross-XCD split).
// ---------------------------------------------------------------------------
__global__ __launch_bounds__(256)
__attribute__((amdgpu_waves_per_eu(2, 3)))
void deform_kernel(
    const float* __restrict__ x, const float* __restrict__ off,
    const short* __restrict__ wf, float* __restrict__ out)
{
  __shared__ __align__(16) char sxb[NSITE * SSTR];   // 23,520 B

  const int b    = blockIdx.y;
  const int bxh  = blockIdx.x;                       // hardware block id
  const int bx   = (bxh & 7) * 128 + (bxh >> 3);     // T1 bijective XCD swizzle
  const int r0   = (bx & 3) * 64;
  const int c0   = bx >> 2;
  const int tid  = threadIdx.x;
  const int lane = tid & 63;
  const int i    = lane & 15;
  const int a    = (lane >> 4) & 3;
  const int oct  = a & 1;
  const int half = a >> 1;
  const int wv   = tid >> 6;
  const int r    = r0 + wv * 16 + i;                 // this thread's pixel row

  // ---- corner tables: 1 site + (wxl,wyl) per tap (verified R8) -----------
  unsigned qsite[5];
  float    qwx[5], qwy[5];
  unsigned inwm = 0;
  const float* obp = off + (size_t)(b * HW + c0) * 18 * HW;
#pragma unroll
  for (int t5 = 0; t5 < 5; ++t5) {
    const int  n9  = 2 * t5 + half;
    const bool pad = (n9 >= 9);
    const int  n   = pad ? 0 : n9;
    const float ox = obp[(size_t)n * HW + r];
    const float oy = obp[(size_t)(9 + n) * HW + r];
    const float px = (float)(c0 + (n % 3)) + ox;     // transposed base: row ~ c
    const float py = (float)(r + (n / 3)) + oy;      // col ~ r
    const float fx = floorf(px);
    const float fy = floorf(py);
    const int ltx = (int)fx, lty = (int)fy;
    const bool okc = (ltx >= 0) & (lty >= 0) & (ltx + 1 <= HW + 1) & (lty + 1 <= HW + 1);
    const int lx = ltx - c0 + 2;                     // window-local row
    const int ly = lty - r0 + 2;                     // window-local col
    const bool inw = okc & (lx >= 0) & (lx <= RXN - 2) & (ly >= 0) & (ly <= CYN - 2);
    qsite[t5] = (pad || !inw) ? 0u : (unsigned)(lx * CYN + ly);
    qwx[t5]   = 1.f + fx - px;                       // wxl (exact in fast path)
    qwy[t5]   = 1.f + fy - py;                       // wyl
    inwm |= ((inw || pad) ? 1u : 0u) << t5;
  }

  // ---- staging site descriptors (sites tid and tid+256) ------------------
  const int s1 = tid, s2 = tid + 256;
  int gi1 = 0, gi2 = 0; bool ok1, ok2;
  {
    const int rxl = s1 / CYN, cyl = s1 - rxl * CYN;
    const int rx = c0 - 2 + rxl, cyp = r0 - 2 + cyl;
    ok1 = (rx >= 1) & (rx <= HW) & (cyp >= 1) & (cyp <= HW);
    if (ok1) gi1 = (rx - 1) * HW + (cyp - 1);
  }
  {
    const int rxl = s2 / CYN, cyl = s2 - rxl * CYN;
    const int rx = c0 - 2 + rxl, cyp = r0 - 2 + cyl;
    ok2 = (s2 < NSITE) & (rx >= 1) & (rx <= HW) & (cyp >= 1) & (cyp <= HW);
    if (ok2) gi2 = (rx - 1) * HW + (cyp - 1);
  }

  const float* xb = x + (size_t)b * CIN * HW2;

  // ---- T14 pipeline registers: round's 32 staging floats -----------------
  float pv1[16], pv2[16];

#define LOADR(RHO)                                                         \
  {                                                                        \
    const float* xsrc = xb + (size_t)((RHO) * 16) * HW2;                   \
    _Pragma("unroll")                                                      \
    for (int m = 0; m < 16; ++m) {                                         \
      const float* xp = xsrc + (size_t)m * HW2;                            \
      pv1[m] = ok1 ? xp[gi1] : 0.f;                                        \
      pv2[m] = ok2 ? xp[gi2] : 0.f;                                        \
    }                                                                      \
  }

#define WRITES()                                                           \
  {                                                                        \
    uint4v w0, w1;                                                         \
    _Pragma("unroll")                                                      \
    for (int m = 0; m < 4; ++m) w0[m] = cvt_pk_bf16(pv1[2*m], pv1[2*m+1]); \
    _Pragma("unroll")                                                      \
    for (int m = 0; m < 4; ++m) w1[m] = cvt_pk_bf16(pv1[8+2*m], pv1[9+2*m]);\
    *(uint4v*)(sxb + s1 * SSTR)      = w0;                                 \
    *(uint4v*)(sxb + s1 * SSTR + 16) = w1;                                 \
    if (s2 < NSITE) {                                                      \
      uint4v u0, u1;                                                       \
      _Pragma("unroll")                                                    \
      for (int m = 0; m < 4; ++m) u0[m] = cvt_pk_bf16(pv2[2*m], pv2[2*m+1]);\
      _Pragma("unroll")                                                    \
      for (int m = 0; m < 4; ++m) u1[m] = cvt_pk_bf16(pv2[8+2*m], pv2[9+2*m]);\
      *(uint4v*)(sxb + s2 * SSTR)      = u0;                               \
      *(uint4v*)(sxb + s2 * SSTR + 16) = u1;                               \
    }                                                                      \
  }

  f32x4 acc[4];
#pragma unroll
  for (int t = 0; t < 4; ++t) acc[t] = (f32x4){0.f, 0.f, 0.f, 0.f};

  // prologue: stage round 0
  LOADR(0)
  WRITES()
  __syncthreads();

#pragma unroll 1
  for (int rho = 0; rho < 4; ++rho) {
    // issue next round's loads early (latency hides under tap loop)
    if (rho < 3) LOADR(rho + 1)

    const short* wfr = wf + ((size_t)(rho * 5 * 4) * 64 + lane) * 8;
    const char*  sbo = sxb + oct * 16;               // octet byte offset

    // tap-0 prefetch: corners (LDS) AND A-frags (global) ping-pong sets
    uint4v nA, nB, nC, nD;
    short8v nf0, nf1, nf2, nf3;
    {
      const char* pb_ = sbo + qsite[0] * SSTR;
      nA = *(const uint4v*)(pb_);
      nC = *(const uint4v*)(pb_ + SSTR);
      nD = *(const uint4v*)(pb_ + 70 * SSTR);
      nB = *(const uint4v*)(pb_ + 71 * SSTR);
      nf0 = *(const short8v*)(wfr);
      nf1 = *(const short8v*)(wfr + 1 * 64 * 8);
      nf2 = *(const short8v*)(wfr + 2 * 64 * 8);
      nf3 = *(const short8v*)(wfr + 3 * 64 * 8);
    }

#define TAPBODY(J)                                                          \
    {                                                                       \
      const short8v af0 = nf0, af1 = nf1, af2 = nf2, af3 = nf3;             \
      const uint4v A = nA, B = nB, C = nC, D = nD;                          \
      if ((J) < 4) {  /* prefetch NEXT tap's corners + A-frags (idx         \
                         clamped: dead arm at J=4 must be in-bounds) */     \
        const char* pb_ = sbo + qsite[(J) < 4 ? (J) + 1 : 0] * SSTR;        \
        nA = *(const uint4v*)(pb_);                                         \
        nC = *(const uint4v*)(pb_ + SSTR);                                  \
        nD = *(const uint4v*)(pb_ + 70 * SSTR);                             \
        nB = *(const uint4v*)(pb_ + 71 * SSTR);                             \
        const short* wfb_ = wfr + (size_t)((J) + 1) * 4 * 64 * 8;           \
        nf0 = *(const short8v*)(wfb_);                                      \
        nf1 = *(const short8v*)(wfb_ + 1 * 64 * 8);                         \
        nf2 = *(const short8v*)(wfb_ + 2 * 64 * 8);                         \
        nf3 = *(const short8v*)(wfb_ + 3 * 64 * 8);                         \
      }                                                                     \
      short8v bfr;                                                          \
      if (__all((inwm >> (J)) & 1)) {                                       \
        const float wxl = qwx[J], wyl = qwy[J];                             \
        const float wxr = 1.f - wxl, wyr = 1.f - wyl;                       \
        const float g0 = wxl * wyl, g1 = wxr * wyr;                         \
        const float g2 = wxl * wyr, g3 = wxr * wyl;                         \
        uint4v bw;                                                          \
        _Pragma("unroll")                                                   \
        for (int m = 0; m < 4; ++m) {                                       \
          const float alo = __uint_as_float(A[m] << 16);                    \
          const float ahi = __uint_as_float(A[m] & 0xFFFF0000u);            \
          const float blo = __uint_as_float(B[m] << 16);                    \
          const float bhi = __uint_as_float(B[m] & 0xFFFF0000u);            \
          const float clo = __uint_as_float(C[m] << 16);                    \
          const float chi = __uint_as_float(C[m] & 0xFFFF0000u);            \
          const float dlo = __uint_as_float(D[m] << 16);                    \
          const float dhi = __uint_as_float(D[m] & 0xFFFF0000u);            \
          float sl = g0 * alo;                                              \
          sl = fmaf(g1, blo, sl); sl = fmaf(g2, clo, sl);                   \
          sl = fmaf(g3, dlo, sl);                                           \
          float sh = g0 * ahi;                                              \
          sh = fmaf(g1, bhi, sh); sh = fmaf(g2, chi, sh);                   \
          sh = fmaf(g3, dhi, sh);                                           \
          bw[m] = cvt_pk_bf16(sl, sh);                                      \
        }                                                                   \
        bfr = __builtin_bit_cast(short8v, bw);                              \
      } else {                                                              \
        /* fallback: exact-original-math global fp32 gather for this tap */ \
        const int  n9_  = 2 * (J) + half;                                   \
        const bool pad_ = (n9_ >= 9);                                       \
        const int  n_   = pad_ ? 0 : n9_;                                   \
        const float ox_ = obp[(size_t)n_ * HW + r];                         \
        const float oy_ = obp[(size_t)(9 + n_) * HW + r];                   \
        const float px_ = (float)(c0 + (n_ % 3)) + ox_;                     \
        const float py_ = (float)(r + (n_ / 3)) + oy_;                      \
        const float fx_ = floorf(px_);                                      \
        const float fy_ = floorf(py_);                                      \
        int ltx_ = (int)fx_, lty_ = (int)fy_;                               \
        int rbx_ = ltx_ + 1, rby_ = lty_ + 1;                               \
        ltx_ = min(max(ltx_, 0), HW + 1); lty_ = min(max(lty_, 0), HW + 1); \
        rbx_ = min(max(rbx_, 0), HW + 1); rby_ = min(max(rby_, 0), HW + 1); \
        const float pxc_ = fminf(fmaxf(px_, 0.f), (float)(HW + 1));         \
        const float pyc_ = fminf(fmaxf(py_, 0.f), (float)(HW + 1));         \
        const float wxl_ = 1.f + (float)ltx_ - pxc_;                        \
        const float wxr_ = 1.f - ((float)rbx_ - pxc_);                      \
        const float wyl_ = 1.f + (float)lty_ - pyc_;                        \
        const float wyr_ = 1.f - ((float)rby_ - pyc_);                      \
        const int   cxs_[4] = { ltx_, rbx_, ltx_, rbx_ };                   \
        const int   cys_[4] = { lty_, rby_, rby_, lty_ };                   \
        const float cgs_[4] = { wxl_ * wyl_, wxr_ * wyr_,                   \
                                wxl_ * wyr_, wxr_ * wyl_ };                 \
        int gi_[4]; float gw_[4];                                           \
        _Pragma("unroll")                                                   \
        for (int k = 0; k < 4; ++k) {                                       \
          const bool ok_ = (cxs_[k] >= 1) & (cxs_[k] <= HW) &               \
                           (cys_[k] >= 1) & (cys_[k] <= HW);                \
          gi_[k] = ok_ ? ((cxs_[k] - 1) * HW + (cys_[k] - 1)) : 0;          \
          gw_[k] = (ok_ && !pad_) ? cgs_[k] : 0.f;                          \
        }                                                                   \
        const float* xpl_ = xb + (size_t)(rho * 16 + oct * 8) * HW2;        \
        _Pragma("unroll")                                                   \
        for (int e = 0; e < 8; ++e) {                                       \
          const float* xe_ = xpl_ + (size_t)e * HW2;                        \
          float sv_ = gw_[0] * xe_[gi_[0]];                                 \
          sv_ = fmaf(gw_[1], xe_[gi_[1]], sv_);                             \
          sv_ = fmaf(gw_[2], xe_[gi_[2]], sv_);                             \
          sv_ = fmaf(gw_[3], xe_[gi_[3]], sv_);                             \
          bfr[e] = (short)f2bf(sv_);                                        \
        }                                                                   \
      }                                                                     \
      acc[0] = __builtin_amdgcn_mfma_f32_16x16x32_bf16(af0, bfr, acc[0], 0, 0, 0); \
      acc[1] = __builtin_amdgcn_mfma_f32_16x16x32_bf16(af1, bfr, acc[1], 0, 0, 0); \
      acc[2] = __builtin_amdgcn_mfma_f32_16x16x32_bf16(af2, bfr, acc[2], 0, 0, 0); \
      acc[3] = __builtin_amdgcn_mfma_f32_16x16x32_bf16(af3, bfr, acc[3], 0, 0, 0); \
    }

    TAPBODY(0) TAPBODY(1) TAPBODY(2) TAPBODY(3) TAPBODY(4)
#undef TAPBODY

    __syncthreads();                                 // window free to overwrite
    if (rho < 3) {
      WRITES()
      __syncthreads();                               // window ready for rho+1
    }
  }

  // C/D store (R2-verified): col = i = pixel, row(oc) = t*16 + a*4 + jj.
#pragma unroll
  for (int t = 0; t < 4; ++t)
#pragma unroll
    for (int jj = 0; jj < 4; ++jj) {
      const int oc = t * 16 + a * 4 + jj;
      out[((size_t)(b * COUT + oc)) * HW2 + (size_t)r * HW + c0] = acc[t][jj];
    }
#undef LOADR
#undef WRITES
}

// ---------------------------------------------------------------------------
extern "C" void kernel_launch(void* const* d_in, const int* in_sizes, int n_in,
                              void* d_out, int out_size, void* d_ws, size_t ws_size,
                              hipStream_t stream) {
  const float* x  = (const float*)d_in[0];   // (2,64,256,256)
  const float* pw = (const float*)d_in[1];   // (18,64,3,3)
  const float* pb = (const float*)d_in[2];   // (18,)
  const float* w  = (const float*)d_in[3];   // (64,64,3,3)
  float* out = (float*)d_out;                // (2,64,256,256)

  char* wsb = (char*)d_ws;
  float* off = (float*)wsb;                                  // 9,437,184 B
  short* wfg = (short*)(wsb + (size_t)2 * 18 * HW2 * 4);     // 81,920 B
  short* wf2 = (short*)(wsb + (size_t)2 * 18 * HW2 * 4 + 81920); // 40,960 B

  wfrag_kernel<<<30, 256, 0, stream>>>(w, pw, wfg, wf2);
  dim3 grid(1024, 2);
  offs_mfma_kernel<<<grid, 256, 0, stream>>>(x, wf2, pb, off);
  deform_kernel<<<grid, 256, 0, stream>>>(x, off, wfg, out);
}